// Round 1
// baseline (92.540 us; speedup 1.0000x reference)
//
#include <hip/hip_runtime.h>

#define M_DIM 16384
#define N_DIM 1024
#define K_DIM 1024

typedef short v8s __attribute__((ext_vector_type(8)));
typedef float v4f __attribute__((ext_vector_type(4)));

__device__ __forceinline__ unsigned short f2bf(float f) {
  // round-to-nearest-even f32 -> bf16 (inputs are finite)
  unsigned u = __float_as_uint(f);
  unsigned r = (u + 0x7FFFu + ((u >> 16) & 1u)) >> 16;
  return (unsigned short)r;
}

__device__ __forceinline__ void gload16(const void* g, void* l) {
  __builtin_amdgcn_global_load_lds(
      (const __attribute__((address_space(1))) void*)g,
      (__attribute__((address_space(3))) void*)l, 16, 0, 0);
}

// ---------- stage 1: per-block max/min partials over weight ----------
__global__ void wminmax_part(const float* __restrict__ w, float* __restrict__ part) {
  int tid = blockIdx.x * 256 + threadIdx.x;
  float mx = -3.402823466e38f, mn = 3.402823466e38f;
  for (int i = tid; i < N_DIM * K_DIM; i += 256 * 256) {
    float v = w[i];
    mx = fmaxf(mx, v);
    mn = fminf(mn, v);
  }
  #pragma unroll
  for (int o = 32; o > 0; o >>= 1) {
    mx = fmaxf(mx, __shfl_down(mx, o));
    mn = fminf(mn, __shfl_down(mn, o));
  }
  __shared__ float smx[4], smn[4];
  int lane = threadIdx.x & 63, wv = threadIdx.x >> 6;
  if (lane == 0) { smx[wv] = mx; smn[wv] = mn; }
  __syncthreads();
  if (threadIdx.x == 0) {
    mx = fmaxf(fmaxf(smx[0], smx[1]), fmaxf(smx[2], smx[3]));
    mn = fminf(fminf(smn[0], smn[1]), fminf(smn[2], smn[3]));
    part[blockIdx.x] = mx;
    part[256 + blockIdx.x] = mn;
  }
}

// ---------- stage 2: final max/min ----------
__global__ void wminmax_final(const float* __restrict__ part, float* __restrict__ mm) {
  float mx = part[threadIdx.x];
  float mn = part[256 + threadIdx.x];
  #pragma unroll
  for (int o = 32; o > 0; o >>= 1) {
    mx = fmaxf(mx, __shfl_down(mx, o));
    mn = fminf(mn, __shfl_down(mn, o));
  }
  __shared__ float smx[4], smn[4];
  int lane = threadIdx.x & 63, wv = threadIdx.x >> 6;
  if (lane == 0) { smx[wv] = mx; smn[wv] = mn; }
  __syncthreads();
  if (threadIdx.x == 0) {
    mm[0] = fmaxf(fmaxf(smx[0], smx[1]), fmaxf(smx[2], smx[3]));
    mm[1] = fminf(fminf(smn[0], smn[1]), fminf(smn[2], smn[3]));
  }
}

// ---------- stage 3: fake-quant weight -> bf16 ----------
__global__ void quant_kernel(const float* __restrict__ w, const float* __restrict__ mm,
                             unsigned short* __restrict__ wq) {
  const float mx = mm[0], mn = mm[1];
  const float alpha = mx - mn, beta = mn;
  int i = (blockIdx.x * 256 + threadIdx.x) * 4;
  float4 v = *(const float4*)(w + i);
  float f[4] = {v.x, v.y, v.z, v.w};
  ushort4 o;
  unsigned short ov[4];
  #pragma unroll
  for (int j = 0; j < 4; j++) {
    // exact op sequence of the reference (fp32, true divisions, rint = round-half-even)
    float s = (f[j] - beta) / alpha;
    float R = rintf(15.0f * s) / 15.0f;
    float q = alpha * R + beta;
    if (f[j] == 0.0f) q = 0.0f;
    ov[j] = f2bf(q);
  }
  o.x = ov[0]; o.y = ov[1]; o.z = ov[2]; o.w = ov[3];
  *(ushort4*)(wq + i) = o;
}

// ---------- stage 4: bf16 MFMA GEMM, y = x @ Wq^T + bias ----------
// 128x128 tile, BK=32, 4 waves (2x2), each wave 64x64 = 4x4 frags of 16x16x32.
__global__ __launch_bounds__(256) void gemm_kernel(
    const float* __restrict__ x, const unsigned short* __restrict__ wq,
    const float* __restrict__ bias, float* __restrict__ out) {
  __shared__ __attribute__((aligned(16))) unsigned short As[128][32];  // [m][k] 8KB
  __shared__ __attribute__((aligned(16))) unsigned short Bs[128][32];  // [n][k] 8KB

  const int tid = threadIdx.x;
  const int lane = tid & 63;
  const int wv = tid >> 6;
  const int wr = wv >> 1, wc = wv & 1;
  const int bm = blockIdx.x, bn = blockIdx.y;

  // A staging: each thread owns 16 consecutive f32 of one row (half a BK row)
  const int arow = tid >> 1;
  const int acol = (tid & 1) << 4;  // 0 or 16
  const float* aptr = x + (size_t)(bm * 128 + arow) * K_DIM + acol;

  // B staging via global_load_lds: wave wv covers chunks {2wv, 2wv+1}; each
  // chunk = 16 rows of Bs = 1KB; lane l -> row chunk*16 + l/4, k (l&3)*8.
  const int chunk0 = wv * 2;
  const int bnl0 = chunk0 * 16 + (lane >> 2);
  const int bk0 = (lane & 3) * 8;
  const unsigned short* bptr0 = wq + (size_t)(bn * 128 + bnl0) * K_DIM + bk0;
  const unsigned short* bptr1 = bptr0 + (size_t)16 * K_DIM;
  unsigned short* ldsb0 = &Bs[chunk0 * 16][0];
  unsigned short* ldsb1 = &Bs[chunk0 * 16 + 16][0];

  v4f acc[4][4];
  #pragma unroll
  for (int i = 0; i < 4; i++)
    #pragma unroll
    for (int j = 0; j < 4; j++) acc[i][j] = (v4f)(0.0f);

  float4 areg[4];
  #pragma unroll
  for (int j = 0; j < 4; j++) areg[j] = *(const float4*)(aptr + j * 4);

  const int frow = lane & 15;        // fragment row/col within 16
  const int fk = (lane >> 4) * 8;    // fragment k base

  for (int kt = 0; kt < K_DIM / 32; ++kt) {
    __syncthreads();
    // A: convert regs -> bf16 -> LDS
    {
      union { v8s v; unsigned short u[8]; } cv0, cv1;
      const float* f = (const float*)areg;
      #pragma unroll
      for (int i = 0; i < 8; i++) {
        cv0.u[i] = f2bf(f[i]);
        cv1.u[i] = f2bf(f[i + 8]);
      }
      *(v8s*)&As[arow][acol] = cv0.v;
      *(v8s*)&As[arow][acol + 8] = cv1.v;
    }
    // B: async global->LDS (bf16 already)
    gload16(bptr0 + (size_t)kt * 32, ldsb0);
    gload16(bptr1 + (size_t)kt * 32, ldsb1);
    // prefetch next A tile into regs (overlaps with compute below)
    if (kt + 1 < K_DIM / 32) {
      const float* ap = aptr + (kt + 1) * 32;
      #pragma unroll
      for (int j = 0; j < 4; j++) areg[j] = *(const float4*)(ap + j * 4);
    }
    __syncthreads();  // drains vmcnt/lgkmcnt: staging complete
    // compute
    v8s af[4], bf[4];
    #pragma unroll
    for (int m = 0; m < 4; m++)
      af[m] = *(const v8s*)&As[wr * 64 + m * 16 + frow][fk];
    #pragma unroll
    for (int n = 0; n < 4; n++)
      bf[n] = *(const v8s*)&Bs[wc * 64 + n * 16 + frow][fk];
    #pragma unroll
    for (int m = 0; m < 4; m++)
      #pragma unroll
      for (int n = 0; n < 4; n++)
        acc[m][n] = __builtin_amdgcn_mfma_f32_16x16x32_bf16(af[m], bf[n], acc[m][n], 0, 0, 0);
  }

  // epilogue: C/D layout col = lane&15, row = (lane>>4)*4 + reg  [m89-verified]
  const int colbase = bn * 128 + wc * 64;
  const int rowbase = bm * 128 + wr * 64;
  #pragma unroll
  for (int n = 0; n < 4; n++) {
    const int col = colbase + n * 16 + (lane & 15);
    const float bv = bias[col];
    #pragma unroll
    for (int m = 0; m < 4; m++) {
      const int row0 = rowbase + m * 16 + (lane >> 4) * 4;
      #pragma unroll
      for (int r = 0; r < 4; r++)
        out[(size_t)(row0 + r) * N_DIM + col] = acc[m][n][r] + bv;
    }
  }
}

extern "C" void kernel_launch(void* const* d_in, const int* in_sizes, int n_in,
                              void* d_out, int out_size, void* d_ws, size_t ws_size,
                              hipStream_t stream) {
  const float* x = (const float*)d_in[0];      // 16384 x 1024
  const float* wt = (const float*)d_in[1];     // 1024 x 1024 (n, m)
  const float* bias = (const float*)d_in[2];   // 1024
  float* out = (float*)d_out;                  // 16384 x 1024

  // ws layout: [0..511] partials (max|min), [512..513] final max/min,
  // [1024 floats ..] = 1M ushort quantized bf16 weight (2MB). Total < 2.1MB.
  float* part = (float*)d_ws;
  float* mm = part + 512;
  unsigned short* wqbuf = (unsigned short*)(part + 1024);

  wminmax_part<<<256, 256, 0, stream>>>(wt, part);
  wminmax_final<<<1, 256, 0, stream>>>(part, mm);
  quant_kernel<<<1024, 256, 0, stream>>>(wt, mm, wqbuf);
  dim3 grid(128, 8);
  gemm_kernel<<<grid, 256, 0, stream>>>(x, wqbuf, bias, out);
}

// Round 2
// 87.622 us; speedup vs baseline: 1.0561x; 1.0561x over previous
//
#include <hip/hip_runtime.h>

#define M_DIM 16384
#define N_DIM 1024
#define K_DIM 1024
#define KTILES (K_DIM / 32)

typedef short v8s __attribute__((ext_vector_type(8)));
typedef float v4f __attribute__((ext_vector_type(4)));

__device__ __forceinline__ unsigned short f2bf(float f) {
  // round-to-nearest-even f32 -> bf16 (inputs finite)
  unsigned u = __float_as_uint(f);
  unsigned r = (u + 0x7FFFu + ((u >> 16) & 1u)) >> 16;
  return (unsigned short)r;
}

__device__ __forceinline__ void gload16(const void* g, void* l) {
  __builtin_amdgcn_global_load_lds(
      (const __attribute__((address_space(1))) void*)g,
      (__attribute__((address_space(3))) void*)l, 16, 0, 0);
}

// ---------- stage 1: per-block max/min partials over weight ----------
__global__ void wminmax_part(const float* __restrict__ w, float* __restrict__ part) {
  int tid = blockIdx.x * 256 + threadIdx.x;
  float mx = -3.402823466e38f, mn = 3.402823466e38f;
  for (int i = tid; i < N_DIM * K_DIM; i += 256 * 256) {
    float v = w[i];
    mx = fmaxf(mx, v);
    mn = fminf(mn, v);
  }
  #pragma unroll
  for (int o = 32; o > 0; o >>= 1) {
    mx = fmaxf(mx, __shfl_down(mx, o));
    mn = fminf(mn, __shfl_down(mn, o));
  }
  __shared__ float smx[4], smn[4];
  int lane = threadIdx.x & 63, wv = threadIdx.x >> 6;
  if (lane == 0) { smx[wv] = mx; smn[wv] = mn; }
  __syncthreads();
  if (threadIdx.x == 0) {
    mx = fmaxf(fmaxf(smx[0], smx[1]), fmaxf(smx[2], smx[3]));
    mn = fminf(fminf(smn[0], smn[1]), fminf(smn[2], smn[3]));
    part[blockIdx.x] = mx;
    part[256 + blockIdx.x] = mn;
  }
}

// ---------- stage 2: final max/min ----------
__global__ void wminmax_final(const float* __restrict__ part, float* __restrict__ mm) {
  float mx = part[threadIdx.x];
  float mn = part[256 + threadIdx.x];
  #pragma unroll
  for (int o = 32; o > 0; o >>= 1) {
    mx = fmaxf(mx, __shfl_down(mx, o));
    mn = fminf(mn, __shfl_down(mn, o));
  }
  __shared__ float smx[4], smn[4];
  int lane = threadIdx.x & 63, wv = threadIdx.x >> 6;
  if (lane == 0) { smx[wv] = mx; smn[wv] = mn; }
  __syncthreads();
  if (threadIdx.x == 0) {
    mm[0] = fmaxf(fmaxf(smx[0], smx[1]), fmaxf(smx[2], smx[3]));
    mm[1] = fminf(fminf(smn[0], smn[1]), fminf(smn[2], smn[3]));
  }
}

// ---------- stage 3: fake-quant weight -> bf16 ----------
__global__ void quant_kernel(const float* __restrict__ w, const float* __restrict__ mm,
                             unsigned short* __restrict__ wq) {
  const float mx = mm[0], mn = mm[1];
  const float alpha = mx - mn, beta = mn;
  int i = (blockIdx.x * 256 + threadIdx.x) * 4;
  float4 v = *(const float4*)(w + i);
  float f[4] = {v.x, v.y, v.z, v.w};
  ushort4 o;
  unsigned short ov[4];
  #pragma unroll
  for (int j = 0; j < 4; j++) {
    float s = (f[j] - beta) / alpha;
    float R = rintf(15.0f * s) / 15.0f;
    float q = alpha * R + beta;
    if (f[j] == 0.0f) q = 0.0f;
    ov[j] = f2bf(q);
  }
  o.x = ov[0]; o.y = ov[1]; o.z = ov[2]; o.w = ov[3];
  *(ushort4*)(wq + i) = o;
}

// ---------- stage 4: bf16 MFMA GEMM, y = x @ Wq^T + bias ----------
// 128x128 tile, BK=32, 4 waves (2x2), double-buffered LDS, 1 barrier/iter.
// LDS swizzle: 16B chunk c of row r stored at chunk c ^ ((r>>1)&3) -> the 16
// rows a quarter-wave reads hit each 16B bank-slot exactly 2x (conflict-free).
// A: reg-staged f32->bf16 (swizzle both sides). B: global_load_lds with
// linear LDS dest + pre-swizzled per-lane GLOBAL source (rule #21).
__global__ __launch_bounds__(256) void gemm_kernel(
    const float* __restrict__ x, const unsigned short* __restrict__ wq,
    const float* __restrict__ bias, float* __restrict__ out) {
  __shared__ __attribute__((aligned(16))) unsigned short As[2][128][32];  // 16KB
  __shared__ __attribute__((aligned(16))) unsigned short Bs[2][128][32];  // 16KB

  const int tid = threadIdx.x;
  const int lane = tid & 63;
  const int wv = tid >> 6;
  const int wr = wv >> 1, wc = wv & 1;
  const int bm = blockIdx.x, bn = blockIdx.y;

  // A staging: thread owns 16 consecutive f32 of row arow (half a BK row)
  const int arow = tid >> 1;
  const int acol = (tid & 1) << 4;
  const float* aptr = x + (size_t)(bm * 128 + arow) * K_DIM + acol;
  const int fA = (arow >> 1) & 3;
  const int ac0 = (tid & 1) * 2;          // first 16B chunk owned (0 or 2)
  const int aw0 = ((ac0) ^ fA) * 8;       // swizzled elem offsets for 2 stores
  const int aw1 = ((ac0 + 1) ^ fA) * 8;

  // B staging: wave wv stages rows wv*32 .. wv*32+31 (two gloads of 16 rows).
  // LDS dest linear: lane l -> row wv*32+(l>>2), chunk l&3. Source chunk is
  // pre-swizzled: (l&3) ^ F(row), F(row) = (row>>1)&3 = (l>>3)&3 here.
  const int brow0 = wv * 32 + (lane >> 2);
  const int bsrcc = (lane & 3) ^ ((lane >> 3) & 3);
  const unsigned short* bptr0 = wq + (size_t)(bn * 128 + brow0) * K_DIM + bsrcc * 8;
  const unsigned short* bptr1 = bptr0 + (size_t)16 * K_DIM;

  v4f acc[4][4];
  #pragma unroll
  for (int i = 0; i < 4; i++)
    #pragma unroll
    for (int j = 0; j < 4; j++) acc[i][j] = (v4f)(0.0f);

  // fragment read addressing (swizzled)
  const int frow = lane & 15;
  const int fkc = lane >> 4;                        // k-chunk 0..3
  const int fsw = (fkc ^ ((frow >> 1) & 3)) * 8;    // swizzled elem offset

  float4 areg[4];
  #pragma unroll
  for (int j = 0; j < 4; j++) areg[j] = *(const float4*)(aptr + j * 4);

  // ---- prologue: stage tile 0 into buffer 0 ----
  {
    const float* f = (const float*)areg;
    union { v8s v; unsigned short u[8]; } cv0, cv1;
    #pragma unroll
    for (int i = 0; i < 8; i++) { cv0.u[i] = f2bf(f[i]); cv1.u[i] = f2bf(f[i + 8]); }
    *(v8s*)&As[0][arow][aw0] = cv0.v;
    *(v8s*)&As[0][arow][aw1] = cv1.v;
    gload16(bptr0, &Bs[0][wv * 32][0]);
    gload16(bptr1, &Bs[0][wv * 32 + 16][0]);
  }
  // prefetch tile 1 A into regs
  #pragma unroll
  for (int j = 0; j < 4; j++) areg[j] = *(const float4*)(aptr + 32 + j * 4);
  __syncthreads();

  for (int kt = 0; kt < KTILES; ++kt) {
    const int cur = kt & 1, nxt = cur ^ 1;
    // stage tile kt+1 into buf[nxt] (overlaps with compute below)
    if (kt + 1 < KTILES) {
      const float* f = (const float*)areg;
      union { v8s v; unsigned short u[8]; } cv0, cv1;
      #pragma unroll
      for (int i = 0; i < 8; i++) { cv0.u[i] = f2bf(f[i]); cv1.u[i] = f2bf(f[i + 8]); }
      *(v8s*)&As[nxt][arow][aw0] = cv0.v;
      *(v8s*)&As[nxt][arow][aw1] = cv1.v;
      gload16(bptr0 + (size_t)(kt + 1) * 32, &Bs[nxt][wv * 32][0]);
      gload16(bptr1 + (size_t)(kt + 1) * 32, &Bs[nxt][wv * 32 + 16][0]);
      if (kt + 2 < KTILES) {
        const float* ap = aptr + (kt + 2) * 32;
        #pragma unroll
        for (int j = 0; j < 4; j++) areg[j] = *(const float4*)(ap + j * 4);
      }
    }
    // compute on buf[cur]
    v8s af[4], bf[4];
    #pragma unroll
    for (int m = 0; m < 4; m++)
      af[m] = *(const v8s*)&As[cur][wr * 64 + m * 16 + frow][fsw];
    #pragma unroll
    for (int n = 0; n < 4; n++)
      bf[n] = *(const v8s*)&Bs[cur][wc * 64 + n * 16 + frow][fsw];
    #pragma unroll
    for (int m = 0; m < 4; m++)
      #pragma unroll
      for (int n = 0; n < 4; n++)
        acc[m][n] = __builtin_amdgcn_mfma_f32_16x16x32_bf16(af[m], bf[n], acc[m][n], 0, 0, 0);
    __syncthreads();  // staging of nxt complete; reads of cur done
  }

  // epilogue: C/D layout col = lane&15, row = (lane>>4)*4 + reg  [m89-verified]
  const int colbase = bn * 128 + wc * 64;
  const int rowbase = bm * 128 + wr * 64;
  #pragma unroll
  for (int n = 0; n < 4; n++) {
    const int col = colbase + n * 16 + (lane & 15);
    const float bv = bias[col];
    #pragma unroll
    for (int m = 0; m < 4; m++) {
      const int row0 = rowbase + m * 16 + (lane >> 4) * 4;
      #pragma unroll
      for (int r = 0; r < 4; r++)
        out[(size_t)(row0 + r) * N_DIM + col] = acc[m][n][r] + bv;
    }
  }
}

extern "C" void kernel_launch(void* const* d_in, const int* in_sizes, int n_in,
                              void* d_out, int out_size, void* d_ws, size_t ws_size,
                              hipStream_t stream) {
  const float* x = (const float*)d_in[0];      // 16384 x 1024
  const float* wt = (const float*)d_in[1];     // 1024 x 1024 (n, m)
  const float* bias = (const float*)d_in[2];   // 1024
  float* out = (float*)d_out;                  // 16384 x 1024

  float* part = (float*)d_ws;
  float* mm = part + 512;
  unsigned short* wqbuf = (unsigned short*)(part + 1024);

  wminmax_part<<<256, 256, 0, stream>>>(wt, part);
  wminmax_final<<<1, 256, 0, stream>>>(part, mm);
  quant_kernel<<<1024, 256, 0, stream>>>(wt, mm, wqbuf);
  dim3 grid(128, 8);
  gemm_kernel<<<grid, 256, 0, stream>>>(x, wqbuf, bias, out);
}

// Round 3
// 79.069 us; speedup vs baseline: 1.1704x; 1.1082x over previous
//
#include <hip/hip_runtime.h>

#define M_DIM 16384
#define N_DIM 1024
#define K_DIM 1024

typedef short v8s __attribute__((ext_vector_type(8)));
typedef float v4f __attribute__((ext_vector_type(4)));

__device__ __forceinline__ unsigned short f2bf(float f) {
  // round-to-nearest-even f32 -> bf16 (inputs finite)
  unsigned u = __float_as_uint(f);
  unsigned r = (u + 0x7FFFu + ((u >> 16) & 1u)) >> 16;
  return (unsigned short)r;
}

__device__ __forceinline__ void gload16(const void* g, void* l) {
  __builtin_amdgcn_global_load_lds(
      (const __attribute__((address_space(1))) void*)g,
      (__attribute__((address_space(3))) void*)l, 16, 0, 0);
}

// ---------- stage 1: per-block max/min partials over weight ----------
__global__ void wminmax_part(const float* __restrict__ w, float* __restrict__ part) {
  int tid = blockIdx.x * 256 + threadIdx.x;
  float mx = -3.402823466e38f, mn = 3.402823466e38f;
  for (int i = tid; i < N_DIM * K_DIM; i += 256 * 256) {
    float v = w[i];
    mx = fmaxf(mx, v);
    mn = fminf(mn, v);
  }
  #pragma unroll
  for (int o = 32; o > 0; o >>= 1) {
    mx = fmaxf(mx, __shfl_down(mx, o));
    mn = fminf(mn, __shfl_down(mn, o));
  }
  __shared__ float smx[4], smn[4];
  int lane = threadIdx.x & 63, wv = threadIdx.x >> 6;
  if (lane == 0) { smx[wv] = mx; smn[wv] = mn; }
  __syncthreads();
  if (threadIdx.x == 0) {
    mx = fmaxf(fmaxf(smx[0], smx[1]), fmaxf(smx[2], smx[3]));
    mn = fminf(fminf(smn[0], smn[1]), fminf(smn[2], smn[3]));
    part[blockIdx.x] = mx;
    part[256 + blockIdx.x] = mn;
  }
}

// ---------- stage 2: final max/min ----------
__global__ void wminmax_final(const float* __restrict__ part, float* __restrict__ mm) {
  float mx = part[threadIdx.x];
  float mn = part[256 + threadIdx.x];
  #pragma unroll
  for (int o = 32; o > 0; o >>= 1) {
    mx = fmaxf(mx, __shfl_down(mx, o));
    mn = fminf(mn, __shfl_down(mn, o));
  }
  __shared__ float smx[4], smn[4];
  int lane = threadIdx.x & 63, wv = threadIdx.x >> 6;
  if (lane == 0) { smx[wv] = mx; smn[wv] = mn; }
  __syncthreads();
  if (threadIdx.x == 0) {
    mm[0] = fmaxf(fmaxf(smx[0], smx[1]), fmaxf(smx[2], smx[3]));
    mm[1] = fminf(fminf(smn[0], smn[1]), fminf(smn[2], smn[3]));
  }
}

// ---------- stage 3: fake-quant weight -> bf16 ----------
__global__ void quant_kernel(const float* __restrict__ w, const float* __restrict__ mm,
                             unsigned short* __restrict__ wq) {
  const float mx = mm[0], mn = mm[1];
  const float alpha = mx - mn, beta = mn;
  int i = (blockIdx.x * 256 + threadIdx.x) * 4;
  float4 v = *(const float4*)(w + i);
  float f[4] = {v.x, v.y, v.z, v.w};
  ushort4 o;
  unsigned short ov[4];
  #pragma unroll
  for (int j = 0; j < 4; j++) {
    float s = (f[j] - beta) / alpha;
    float R = rintf(15.0f * s) / 15.0f;
    float q = alpha * R + beta;
    if (f[j] == 0.0f) q = 0.0f;
    ov[j] = f2bf(q);
  }
  o.x = ov[0]; o.y = ov[1]; o.z = ov[2]; o.w = ov[3];
  *(ushort4*)(wq + i) = o;
}

// ---------- stage 3b: x f32 -> bf16 (fast path) ----------
__global__ void conv_kernel(const float* __restrict__ x, unsigned short* __restrict__ xbf) {
  int i = (blockIdx.x * 256 + threadIdx.x) * 8;
  float4 a = *(const float4*)(x + i);
  float4 b = *(const float4*)(x + i + 4);
  union { v8s v; unsigned short u[8]; } o;
  o.u[0] = f2bf(a.x); o.u[1] = f2bf(a.y); o.u[2] = f2bf(a.z); o.u[3] = f2bf(a.w);
  o.u[4] = f2bf(b.x); o.u[5] = f2bf(b.y); o.u[6] = f2bf(b.z); o.u[7] = f2bf(b.w);
  *(v8s*)(xbf + i) = o.v;
}

// ---------- stage 4 (fast): 256x256 tile, BK=32, 8 waves, 4-deep LDS ring,
// counted vmcnt(8) + raw s_barrier (loads never drained to 0 in-loop).
// Swizzle: 16B chunk c of row r stored at c ^ ((r>>1)&3) (proven conflict-free).
// Both operands staged via global_load_lds with pre-swizzled global source.
__global__ __launch_bounds__(512, 2) void gemm256_kernel(
    const unsigned short* __restrict__ xbf, const unsigned short* __restrict__ wq,
    const float* __restrict__ bias, float* __restrict__ out) {
  __shared__ __attribute__((aligned(16))) unsigned short As[4][256][32];  // 64KB
  __shared__ __attribute__((aligned(16))) unsigned short Bs[4][256][32];  // 64KB

  const int tid = threadIdx.x;
  const int lane = tid & 63;
  const int wv = tid >> 6;     // 0..7
  const int wr = wv >> 2;      // 0..1  (M half)
  const int wc = wv & 3;       // 0..3  (N quarter)
  const int bm = blockIdx.x;   // 0..63
  const int bn = blockIdx.y;   // 0..3

  // staging: wave wv owns rows [wv*32, wv*32+32) of the 256-row tile.
  // lane l -> row wv*32 + (l>>2), 16B chunk l&3 (LDS dest is linear);
  // global source chunk pre-swizzled: (l&3) ^ ((row>>1)&3) = (l&3) ^ ((l>>3)&3).
  const int srow = wv * 32 + (lane >> 2);
  const int sch = ((lane & 3) ^ ((lane >> 3) & 3)) * 8;
  const unsigned short* aG = xbf + (size_t)(bm * 256 + srow) * K_DIM + sch;
  const unsigned short* bG = wq + (size_t)(bn * 256 + srow) * K_DIM + sch;

  // fragment reads (swizzled)
  const int frow = lane & 15;
  const int fsw = ((lane >> 4) ^ ((frow >> 1) & 3)) * 8;

  v4f acc[8][4];
  #pragma unroll
  for (int m = 0; m < 8; m++)
    #pragma unroll
    for (int n = 0; n < 4; n++) acc[m][n] = (v4f)(0.0f);

  auto STAGE = [&](int kt, int b) {
    gload16(aG + kt * 32, &As[b][wv * 32][0]);
    gload16(aG + kt * 32 + 16 * K_DIM, &As[b][wv * 32 + 16][0]);
    gload16(bG + kt * 32, &Bs[b][wv * 32][0]);
    gload16(bG + kt * 32 + 16 * K_DIM, &Bs[b][wv * 32 + 16][0]);
  };
  auto COMPUTE = [&](int b) {
    v8s af[8], bfv[4];
    #pragma unroll
    for (int m = 0; m < 8; m++)
      af[m] = *(const v8s*)&As[b][wr * 128 + m * 16 + frow][fsw];
    #pragma unroll
    for (int n = 0; n < 4; n++)
      bfv[n] = *(const v8s*)&Bs[b][wc * 64 + n * 16 + frow][fsw];
    __builtin_amdgcn_s_setprio(1);
    #pragma unroll
    for (int m = 0; m < 8; m++)
      #pragma unroll
      for (int n = 0; n < 4; n++)
        acc[m][n] = __builtin_amdgcn_mfma_f32_16x16x32_bf16(af[m], bfv[n], acc[m][n], 0, 0, 0);
    __builtin_amdgcn_s_setprio(0);
  };

  // prologue: 3 ktiles in flight (12 gloads/wave)
  STAGE(0, 0);
  STAGE(1, 1);
  STAGE(2, 2);

  // main: at phase kt, outstanding <= ktiles {kt,kt+1,kt+2} = 12 loads;
  // vmcnt(8) forces ktile kt's 4 loads to land. Buf (kt+3)&3 held ktile
  // kt-1, fully read before every wave passed this barrier -> safe to issue.
  for (int kt = 0; kt < 29; ++kt) {
    asm volatile("s_waitcnt vmcnt(8)" ::: "memory");
    __builtin_amdgcn_s_barrier();
    asm volatile("" ::: "memory");
    STAGE(kt + 3, (kt + 3) & 3);
    COMPUTE(kt & 3);
  }
  // epilogue phases: kt=29 (gate 8), 30 (gate 4), 31 (gate 0)
  asm volatile("s_waitcnt vmcnt(8)" ::: "memory");
  __builtin_amdgcn_s_barrier();
  asm volatile("" ::: "memory");
  COMPUTE(1);
  asm volatile("s_waitcnt vmcnt(4)" ::: "memory");
  __builtin_amdgcn_s_barrier();
  asm volatile("" ::: "memory");
  COMPUTE(2);
  asm volatile("s_waitcnt vmcnt(0)" ::: "memory");
  __builtin_amdgcn_s_barrier();
  asm volatile("" ::: "memory");
  COMPUTE(3);

  // C-write: col = lane&15, row = (lane>>4)*4 + reg  [m89-verified]
  const int colbase = bn * 256 + wc * 64;
  const int rowbase = bm * 256 + wr * 128;
  #pragma unroll
  for (int n = 0; n < 4; n++) {
    const int col = colbase + n * 16 + (lane & 15);
    const float bv = bias[col];
    #pragma unroll
    for (int m = 0; m < 8; m++) {
      const int row0 = rowbase + m * 16 + (lane >> 4) * 4;
      #pragma unroll
      for (int r = 0; r < 4; r++)
        out[(size_t)(row0 + r) * N_DIM + col] = acc[m][n][r] + bv;
    }
  }
}

// ---------- stage 4 (fallback, proven round-2): 128x128, in-GEMM cvt ----------
__global__ __launch_bounds__(256) void gemm_kernel(
    const float* __restrict__ x, const unsigned short* __restrict__ wq,
    const float* __restrict__ bias, float* __restrict__ out) {
  __shared__ __attribute__((aligned(16))) unsigned short As[2][128][32];
  __shared__ __attribute__((aligned(16))) unsigned short Bs[2][128][32];

  const int tid = threadIdx.x;
  const int lane = tid & 63;
  const int wv = tid >> 6;
  const int wr = wv >> 1, wc = wv & 1;
  const int bm = blockIdx.x, bn = blockIdx.y;

  const int arow = tid >> 1;
  const int acol = (tid & 1) << 4;
  const float* aptr = x + (size_t)(bm * 128 + arow) * K_DIM + acol;
  const int fA = (arow >> 1) & 3;
  const int ac0 = (tid & 1) * 2;
  const int aw0 = ((ac0) ^ fA) * 8;
  const int aw1 = ((ac0 + 1) ^ fA) * 8;

  const int brow0 = wv * 32 + (lane >> 2);
  const int bsrcc = (lane & 3) ^ ((lane >> 3) & 3);
  const unsigned short* bptr0 = wq + (size_t)(bn * 128 + brow0) * K_DIM + bsrcc * 8;
  const unsigned short* bptr1 = bptr0 + (size_t)16 * K_DIM;

  v4f acc[4][4];
  #pragma unroll
  for (int i = 0; i < 4; i++)
    #pragma unroll
    for (int j = 0; j < 4; j++) acc[i][j] = (v4f)(0.0f);

  const int frow = lane & 15;
  const int fkc = lane >> 4;
  const int fsw = (fkc ^ ((frow >> 1) & 3)) * 8;

  float4 areg[4];
  #pragma unroll
  for (int j = 0; j < 4; j++) areg[j] = *(const float4*)(aptr + j * 4);

  {
    const float* f = (const float*)areg;
    union { v8s v; unsigned short u[8]; } cv0, cv1;
    #pragma unroll
    for (int i = 0; i < 8; i++) { cv0.u[i] = f2bf(f[i]); cv1.u[i] = f2bf(f[i + 8]); }
    *(v8s*)&As[0][arow][aw0] = cv0.v;
    *(v8s*)&As[0][arow][aw1] = cv1.v;
    gload16(bptr0, &Bs[0][wv * 32][0]);
    gload16(bptr1, &Bs[0][wv * 32 + 16][0]);
  }
  #pragma unroll
  for (int j = 0; j < 4; j++) areg[j] = *(const float4*)(aptr + 32 + j * 4);
  __syncthreads();

  for (int kt = 0; kt < K_DIM / 32; ++kt) {
    const int cur = kt & 1, nxt = cur ^ 1;
    if (kt + 1 < K_DIM / 32) {
      const float* f = (const float*)areg;
      union { v8s v; unsigned short u[8]; } cv0, cv1;
      #pragma unroll
      for (int i = 0; i < 8; i++) { cv0.u[i] = f2bf(f[i]); cv1.u[i] = f2bf(f[i + 8]); }
      *(v8s*)&As[nxt][arow][aw0] = cv0.v;
      *(v8s*)&As[nxt][arow][aw1] = cv1.v;
      gload16(bptr0 + (size_t)(kt + 1) * 32, &Bs[nxt][wv * 32][0]);
      gload16(bptr1 + (size_t)(kt + 1) * 32, &Bs[nxt][wv * 32 + 16][0]);
      if (kt + 2 < K_DIM / 32) {
        const float* ap = aptr + (kt + 2) * 32;
        #pragma unroll
        for (int j = 0; j < 4; j++) areg[j] = *(const float4*)(ap + j * 4);
      }
    }
    v8s af[4], bf[4];
    #pragma unroll
    for (int m = 0; m < 4; m++)
      af[m] = *(const v8s*)&As[cur][wr * 64 + m * 16 + frow][fsw];
    #pragma unroll
    for (int n = 0; n < 4; n++)
      bf[n] = *(const v8s*)&Bs[cur][wc * 64 + n * 16 + frow][fsw];
    #pragma unroll
    for (int m = 0; m < 4; m++)
      #pragma unroll
      for (int n = 0; n < 4; n++)
        acc[m][n] = __builtin_amdgcn_mfma_f32_16x16x32_bf16(af[m], bf[n], acc[m][n], 0, 0, 0);
    __syncthreads();
  }

  const int colbase = bn * 128 + wc * 64;
  const int rowbase = bm * 128 + wr * 64;
  #pragma unroll
  for (int n = 0; n < 4; n++) {
    const int col = colbase + n * 16 + (lane & 15);
    const float bv = bias[col];
    #pragma unroll
    for (int m = 0; m < 4; m++) {
      const int row0 = rowbase + m * 16 + (lane >> 4) * 4;
      #pragma unroll
      for (int r = 0; r < 4; r++)
        out[(size_t)(row0 + r) * N_DIM + col] = acc[m][n][r] + bv;
    }
  }
}

extern "C" void kernel_launch(void* const* d_in, const int* in_sizes, int n_in,
                              void* d_out, int out_size, void* d_ws, size_t ws_size,
                              hipStream_t stream) {
  const float* x = (const float*)d_in[0];      // 16384 x 1024
  const float* wt = (const float*)d_in[1];     // 1024 x 1024 (n, m)
  const float* bias = (const float*)d_in[2];   // 1024
  float* out = (float*)d_out;                  // 16384 x 1024

  // ws layout: [0,4KB) minmax partials+result; [4KB, 4KB+2MB) wq bf16;
  // fast path adds [4KB+2MB, +32MB) x bf16.
  float* part = (float*)d_ws;
  float* mm = part + 512;
  unsigned short* wqbuf = (unsigned short*)((char*)d_ws + 4096);
  unsigned short* xbf = (unsigned short*)((char*)d_ws + 4096 + 2 * 1024 * 1024);
  const size_t need = 4096 + 2ull * 1024 * 1024 + 2ull * M_DIM * K_DIM;

  wminmax_part<<<256, 256, 0, stream>>>(wt, part);
  wminmax_final<<<1, 256, 0, stream>>>(part, mm);
  quant_kernel<<<1024, 256, 0, stream>>>(wt, mm, wqbuf);

  if (ws_size >= need) {
    conv_kernel<<<M_DIM * K_DIM / (8 * 256), 256, 0, stream>>>(x, xbf);
    dim3 grid(M_DIM / 256, N_DIM / 256);
    gemm256_kernel<<<grid, 512, 0, stream>>>(xbf, wqbuf, bias, out);
  } else {
    dim3 grid(M_DIM / 128, N_DIM / 128);
    gemm_kernel<<<grid, 256, 0, stream>>>(x, wqbuf, bias, out);
  }
}

// Round 4
// 72.074 us; speedup vs baseline: 1.2840x; 1.0971x over previous
//
#include <hip/hip_runtime.h>

#define M_DIM 16384
#define N_DIM 1024
#define K_DIM 1024

typedef short v8s __attribute__((ext_vector_type(8)));
typedef float v4f __attribute__((ext_vector_type(4)));

__device__ __forceinline__ unsigned short f2bf(float f) {
  // round-to-nearest-even f32 -> bf16 (inputs finite)
  unsigned u = __float_as_uint(f);
  unsigned r = (u + 0x7FFFu + ((u >> 16) & 1u)) >> 16;
  return (unsigned short)r;
}

__device__ __forceinline__ void gload16(const void* g, void* l) {
  __builtin_amdgcn_global_load_lds(
      (const __attribute__((address_space(1))) void*)g,
      (__attribute__((address_space(3))) void*)l, 16, 0, 0);
}

// inline-asm ds_read_b128: opaque to SIInsertWaitcnts so the compiler cannot
// inject vmcnt(0) to order it against in-flight global_load_lds (we order
// manually via counted vmcnt + barrier). offset must be a string literal.
#define DSR(dst, addr, off) \
  asm volatile("ds_read_b128 %0, %1 offset:" off : "=v"(dst) : "v"(addr))

// ---------- stage 1: per-block max/min partials over weight ----------
__global__ void wminmax_part(const float* __restrict__ w, float* __restrict__ part) {
  int tid = blockIdx.x * 256 + threadIdx.x;
  float mx = -3.402823466e38f, mn = 3.402823466e38f;
  for (int i = tid; i < N_DIM * K_DIM; i += 256 * 256) {
    float v = w[i];
    mx = fmaxf(mx, v);
    mn = fminf(mn, v);
  }
  #pragma unroll
  for (int o = 32; o > 0; o >>= 1) {
    mx = fmaxf(mx, __shfl_down(mx, o));
    mn = fminf(mn, __shfl_down(mn, o));
  }
  __shared__ float smx[4], smn[4];
  int lane = threadIdx.x & 63, wv = threadIdx.x >> 6;
  if (lane == 0) { smx[wv] = mx; smn[wv] = mn; }
  __syncthreads();
  if (threadIdx.x == 0) {
    mx = fmaxf(fmaxf(smx[0], smx[1]), fmaxf(smx[2], smx[3]));
    mn = fminf(fminf(smn[0], smn[1]), fminf(smn[2], smn[3]));
    part[blockIdx.x] = mx;
    part[256 + blockIdx.x] = mn;
  }
}

// ---------- stage 2: final max/min ----------
__global__ void wminmax_final(const float* __restrict__ part, float* __restrict__ mm) {
  float mx = part[threadIdx.x];
  float mn = part[256 + threadIdx.x];
  #pragma unroll
  for (int o = 32; o > 0; o >>= 1) {
    mx = fmaxf(mx, __shfl_down(mx, o));
    mn = fminf(mn, __shfl_down(mn, o));
  }
  __shared__ float smx[4], smn[4];
  int lane = threadIdx.x & 63, wv = threadIdx.x >> 6;
  if (lane == 0) { smx[wv] = mx; smn[wv] = mn; }
  __syncthreads();
  if (threadIdx.x == 0) {
    mm[0] = fmaxf(fmaxf(smx[0], smx[1]), fmaxf(smx[2], smx[3]));
    mm[1] = fminf(fminf(smn[0], smn[1]), fminf(smn[2], smn[3]));
  }
}

// ---------- stage 3: fake-quant weight -> bf16 ----------
__global__ void quant_kernel(const float* __restrict__ w, const float* __restrict__ mm,
                             unsigned short* __restrict__ wq) {
  const float mx = mm[0], mn = mm[1];
  const float alpha = mx - mn, beta = mn;
  int i = (blockIdx.x * 256 + threadIdx.x) * 4;
  float4 v = *(const float4*)(w + i);
  float f[4] = {v.x, v.y, v.z, v.w};
  ushort4 o;
  unsigned short ov[4];
  #pragma unroll
  for (int j = 0; j < 4; j++) {
    float s = (f[j] - beta) / alpha;
    float R = rintf(15.0f * s) / 15.0f;
    float q = alpha * R + beta;
    if (f[j] == 0.0f) q = 0.0f;
    ov[j] = f2bf(q);
  }
  o.x = ov[0]; o.y = ov[1]; o.z = ov[2]; o.w = ov[3];
  *(ushort4*)(wq + i) = o;
}

// ---------- stage 3b: x f32 -> bf16 (fast path) ----------
__global__ void conv_kernel(const float* __restrict__ x, unsigned short* __restrict__ xbf) {
  int i = (blockIdx.x * 256 + threadIdx.x) * 8;
  float4 a = *(const float4*)(x + i);
  float4 b = *(const float4*)(x + i + 4);
  union { v8s v; unsigned short u[8]; } o;
  o.u[0] = f2bf(a.x); o.u[1] = f2bf(a.y); o.u[2] = f2bf(a.z); o.u[3] = f2bf(a.w);
  o.u[4] = f2bf(b.x); o.u[5] = f2bf(b.y); o.u[6] = f2bf(b.z); o.u[7] = f2bf(b.w);
  *(v8s*)(xbf + i) = o.v;
}

// ---------- stage 4 (fast): 256x256 tile, BK=32, 8 waves, 4-deep LDS ring.
// Counted vmcnt(8) + raw s_barrier; fragment reads are INLINE-ASM ds_read_b128
// so the compiler cannot inject a vmcnt(0) drain against in-flight
// global_load_lds. Manual lgkmcnt(0) + sched_barrier(0) before MFMA (rule #18).
__global__ __launch_bounds__(512, 2) void gemm256_kernel(
    const unsigned short* __restrict__ xbf, const unsigned short* __restrict__ wq,
    const float* __restrict__ bias, float* __restrict__ out) {
  __shared__ __attribute__((aligned(16))) unsigned short As[4][256][32];  // 64KB
  __shared__ __attribute__((aligned(16))) unsigned short Bs[4][256][32];  // 64KB

  const int tid = threadIdx.x;
  const int lane = tid & 63;
  const int wv = tid >> 6;     // 0..7
  const int wr = wv >> 2;      // 0..1  (M half)
  const int wc = wv & 3;       // 0..3  (N quarter)
  const int bm = blockIdx.x;   // 0..63
  const int bn = blockIdx.y;   // 0..3

  // staging: wave wv owns rows [wv*32, wv*32+32). LDS dest linear, global
  // source 16B-chunk pre-swizzled by (row>>1)&3 (proven conflict-free r2/r3).
  const int srow = wv * 32 + (lane >> 2);
  const int sch = ((lane & 3) ^ ((lane >> 3) & 3)) * 8;
  const unsigned short* aG = xbf + (size_t)(bm * 256 + srow) * K_DIM + sch;
  const unsigned short* bG = wq + (size_t)(bn * 256 + srow) * K_DIM + sch;

  // fragment read addressing (swizzled), as LDS byte addresses
  const int frow = lane & 15;
  const int fsw = ((lane >> 4) ^ ((frow >> 1) & 3)) * 8;
  const unsigned ldsA0 =
      (unsigned)(unsigned long long)(__attribute__((address_space(3))) unsigned short*)&As[0][0][0];
  const unsigned ldsB0 =
      (unsigned)(unsigned long long)(__attribute__((address_space(3))) unsigned short*)&Bs[0][0][0];
  const unsigned aLane = ldsA0 + ((unsigned)((wr * 128 + frow) * 32 + fsw)) * 2u;
  const unsigned bLane = ldsB0 + ((unsigned)((wc * 64 + frow) * 32 + fsw)) * 2u;

  v4f acc[8][4];
  #pragma unroll
  for (int m = 0; m < 8; m++)
    #pragma unroll
    for (int n = 0; n < 4; n++) acc[m][n] = (v4f)(0.0f);

  auto STAGE = [&](int kt, int b) {
    gload16(aG + kt * 32, &As[b][wv * 32][0]);
    gload16(aG + kt * 32 + 16 * K_DIM, &As[b][wv * 32 + 16][0]);
    gload16(bG + kt * 32, &Bs[b][wv * 32][0]);
    gload16(bG + kt * 32 + 16 * K_DIM, &Bs[b][wv * 32 + 16][0]);
  };

  auto PHASE = [&](int kt, int gate, bool pf) {
    if (gate == 8)      asm volatile("s_waitcnt vmcnt(8)" ::: "memory");
    else if (gate == 4) asm volatile("s_waitcnt vmcnt(4)" ::: "memory");
    else                asm volatile("s_waitcnt vmcnt(0)" ::: "memory");
    __builtin_amdgcn_s_barrier();
    const unsigned boff = (unsigned)(kt & 3) * 16384u;
    const unsigned aP = aLane + boff;
    const unsigned bP = bLane + boff;
    v8s af[8], bf4[4];
    DSR(af[0], aP, "0");
    DSR(af[1], aP, "1024");
    DSR(af[2], aP, "2048");
    DSR(af[3], aP, "3072");
    DSR(af[4], aP, "4096");
    DSR(af[5], aP, "5120");
    DSR(af[6], aP, "6144");
    DSR(af[7], aP, "7168");
    DSR(bf4[0], bP, "0");
    DSR(bf4[1], bP, "1024");
    DSR(bf4[2], bP, "2048");
    DSR(bf4[3], bP, "3072");
    if (pf) STAGE(kt + 3, (kt + 3) & 3);
    asm volatile("s_waitcnt lgkmcnt(0)" ::: "memory");
    __builtin_amdgcn_sched_barrier(0);
    __builtin_amdgcn_s_setprio(1);
    #pragma unroll
    for (int m = 0; m < 8; m++)
      #pragma unroll
      for (int n = 0; n < 4; n++)
        acc[m][n] = __builtin_amdgcn_mfma_f32_16x16x32_bf16(af[m], bf4[n], acc[m][n], 0, 0, 0);
    __builtin_amdgcn_s_setprio(0);
  };

  // prologue: 3 ktiles in flight (12 gloads/wave)
  STAGE(0, 0);
  STAGE(1, 1);
  STAGE(2, 2);

  // main: at phase kt outstanding <= {kt,kt+1,kt+2} = 12 loads; vmcnt(8)
  // lands ktile kt. Buf (kt+3)&3 was fully read at phase kt-1 (before the
  // barrier every wave just passed) -> safe to re-stage.
  for (int kt = 0; kt < 29; ++kt) PHASE(kt, 8, true);
  PHASE(29, 8, false);
  PHASE(30, 4, false);
  PHASE(31, 0, false);

  // C-write: col = lane&15, row = (lane>>4)*4 + reg  [m89-verified]
  const int colbase = bn * 256 + wc * 64;
  const int rowbase = bm * 256 + wr * 128;
  #pragma unroll
  for (int n = 0; n < 4; n++) {
    const int col = colbase + n * 16 + (lane & 15);
    const float bv = bias[col];
    #pragma unroll
    for (int m = 0; m < 8; m++) {
      const int row0 = rowbase + m * 16 + (lane >> 4) * 4;
      #pragma unroll
      for (int r = 0; r < 4; r++)
        out[(size_t)(row0 + r) * N_DIM + col] = acc[m][n][r] + bv;
    }
  }
}

// ---------- stage 4 (fallback, proven round-2): 128x128, in-GEMM cvt ----------
__global__ __launch_bounds__(256) void gemm_kernel(
    const float* __restrict__ x, const unsigned short* __restrict__ wq,
    const float* __restrict__ bias, float* __restrict__ out) {
  __shared__ __attribute__((aligned(16))) unsigned short As[2][128][32];
  __shared__ __attribute__((aligned(16))) unsigned short Bs[2][128][32];

  const int tid = threadIdx.x;
  const int lane = tid & 63;
  const int wv = tid >> 6;
  const int wr = wv >> 1, wc = wv & 1;
  const int bm = blockIdx.x, bn = blockIdx.y;

  const int arow = tid >> 1;
  const int acol = (tid & 1) << 4;
  const float* aptr = x + (size_t)(bm * 128 + arow) * K_DIM + acol;
  const int fA = (arow >> 1) & 3;
  const int ac0 = (tid & 1) * 2;
  const int aw0 = ((ac0) ^ fA) * 8;
  const int aw1 = ((ac0 + 1) ^ fA) * 8;

  const int brow0 = wv * 32 + (lane >> 2);
  const int bsrcc = (lane & 3) ^ ((lane >> 3) & 3);
  const unsigned short* bptr0 = wq + (size_t)(bn * 128 + brow0) * K_DIM + bsrcc * 8;
  const unsigned short* bptr1 = bptr0 + (size_t)16 * K_DIM;

  v4f acc[4][4];
  #pragma unroll
  for (int i = 0; i < 4; i++)
    #pragma unroll
    for (int j = 0; j < 4; j++) acc[i][j] = (v4f)(0.0f);

  const int frow = lane & 15;
  const int fkc = lane >> 4;
  const int fsw = (fkc ^ ((frow >> 1) & 3)) * 8;

  float4 areg[4];
  #pragma unroll
  for (int j = 0; j < 4; j++) areg[j] = *(const float4*)(aptr + j * 4);

  {
    const float* f = (const float*)areg;
    union { v8s v; unsigned short u[8]; } cv0, cv1;
    #pragma unroll
    for (int i = 0; i < 8; i++) { cv0.u[i] = f2bf(f[i]); cv1.u[i] = f2bf(f[i + 8]); }
    *(v8s*)&As[0][arow][aw0] = cv0.v;
    *(v8s*)&As[0][arow][aw1] = cv1.v;
    gload16(bptr0, &Bs[0][wv * 32][0]);
    gload16(bptr1, &Bs[0][wv * 32 + 16][0]);
  }
  #pragma unroll
  for (int j = 0; j < 4; j++) areg[j] = *(const float4*)(aptr + 32 + j * 4);
  __syncthreads();

  for (int kt = 0; kt < K_DIM / 32; ++kt) {
    const int cur = kt & 1, nxt = cur ^ 1;
    if (kt + 1 < K_DIM / 32) {
      const float* f = (const float*)areg;
      union { v8s v; unsigned short u[8]; } cv0, cv1;
      #pragma unroll
      for (int i = 0; i < 8; i++) { cv0.u[i] = f2bf(f[i]); cv1.u[i] = f2bf(f[i + 8]); }
      *(v8s*)&As[nxt][arow][aw0] = cv0.v;
      *(v8s*)&As[nxt][arow][aw1] = cv1.v;
      gload16(bptr0 + (size_t)(kt + 1) * 32, &Bs[nxt][wv * 32][0]);
      gload16(bptr1 + (size_t)(kt + 1) * 32, &Bs[nxt][wv * 32 + 16][0]);
      if (kt + 2 < K_DIM / 32) {
        const float* ap = aptr + (kt + 2) * 32;
        #pragma unroll
        for (int j = 0; j < 4; j++) areg[j] = *(const float4*)(ap + j * 4);
      }
    }
    v8s af[4], bf[4];
    #pragma unroll
    for (int m = 0; m < 4; m++)
      af[m] = *(const v8s*)&As[cur][wr * 64 + m * 16 + frow][fsw];
    #pragma unroll
    for (int n = 0; n < 4; n++)
      bf[n] = *(const v8s*)&Bs[cur][wc * 64 + n * 16 + frow][fsw];
    #pragma unroll
    for (int m = 0; m < 4; m++)
      #pragma unroll
      for (int n = 0; n < 4; n++)
        acc[m][n] = __builtin_amdgcn_mfma_f32_16x16x32_bf16(af[m], bf[n], acc[m][n], 0, 0, 0);
    __syncthreads();
  }

  const int colbase = bn * 128 + wc * 64;
  const int rowbase = bm * 128 + wr * 64;
  #pragma unroll
  for (int n = 0; n < 4; n++) {
    const int col = colbase + n * 16 + (lane & 15);
    const float bv = bias[col];
    #pragma unroll
    for (int m = 0; m < 4; m++) {
      const int row0 = rowbase + m * 16 + (lane >> 4) * 4;
      #pragma unroll
      for (int r = 0; r < 4; r++)
        out[(size_t)(row0 + r) * N_DIM + col] = acc[m][n][r] + bv;
    }
  }
}

extern "C" void kernel_launch(void* const* d_in, const int* in_sizes, int n_in,
                              void* d_out, int out_size, void* d_ws, size_t ws_size,
                              hipStream_t stream) {
  const float* x = (const float*)d_in[0];      // 16384 x 1024
  const float* wt = (const float*)d_in[1];     // 1024 x 1024 (n, m)
  const float* bias = (const float*)d_in[2];   // 1024
  float* out = (float*)d_out;                  // 16384 x 1024

  float* part = (float*)d_ws;
  float* mm = part + 512;
  unsigned short* wqbuf = (unsigned short*)((char*)d_ws + 4096);
  unsigned short* xbf = (unsigned short*)((char*)d_ws + 4096 + 2 * 1024 * 1024);
  const size_t need = 4096 + 2ull * 1024 * 1024 + 2ull * M_DIM * K_DIM;

  wminmax_part<<<256, 256, 0, stream>>>(wt, part);
  wminmax_final<<<1, 256, 0, stream>>>(part, mm);
  quant_kernel<<<1024, 256, 0, stream>>>(wt, mm, wqbuf);

  if (ws_size >= need) {
    conv_kernel<<<M_DIM * K_DIM / (8 * 256), 256, 0, stream>>>(x, xbf);
    dim3 grid(M_DIM / 256, N_DIM / 256);
    gemm256_kernel<<<grid, 512, 0, stream>>>(xbf, wqbuf, bias, out);
  } else {
    dim3 grid(M_DIM / 128, N_DIM / 128);
    gemm_kernel<<<grid, 256, 0, stream>>>(x, wqbuf, bias, out);
  }
}

// Round 5
// 70.314 us; speedup vs baseline: 1.3161x; 1.0250x over previous
//
#include <hip/hip_runtime.h>

#define M_DIM 16384
#define N_DIM 1024
#define K_DIM 1024

typedef short v8s __attribute__((ext_vector_type(8)));
typedef float v4f __attribute__((ext_vector_type(4)));

__device__ __forceinline__ unsigned short f2bf(float f) {
  unsigned u = __float_as_uint(f);
  unsigned r = (u + 0x7FFFu + ((u >> 16) & 1u)) >> 16;
  return (unsigned short)r;
}

__device__ __forceinline__ void gload16(const void* g, void* l) {
  __builtin_amdgcn_global_load_lds(
      (const __attribute__((address_space(1))) void*)g,
      (__attribute__((address_space(3))) void*)l, 16, 0, 0);
}

// inline-asm ds_read_b128: invisible to SIInsertWaitcnts (no forced vmcnt
// drain against in-flight global_load_lds). offset is a string literal.
#define DSR(dst, addr, off) \
  asm volatile("ds_read_b128 %0, %1 offset:" off : "=v"(dst) : "v"(addr))

// ---------- stage 1/2: weight max/min ----------
__global__ void wminmax_part(const float* __restrict__ w, float* __restrict__ part) {
  int tid = blockIdx.x * 256 + threadIdx.x;
  float mx = -3.402823466e38f, mn = 3.402823466e38f;
  for (int i = tid; i < N_DIM * K_DIM; i += 256 * 256) {
    float v = w[i];
    mx = fmaxf(mx, v);
    mn = fminf(mn, v);
  }
  #pragma unroll
  for (int o = 32; o > 0; o >>= 1) {
    mx = fmaxf(mx, __shfl_down(mx, o));
    mn = fminf(mn, __shfl_down(mn, o));
  }
  __shared__ float smx[4], smn[4];
  int lane = threadIdx.x & 63, wv = threadIdx.x >> 6;
  if (lane == 0) { smx[wv] = mx; smn[wv] = mn; }
  __syncthreads();
  if (threadIdx.x == 0) {
    mx = fmaxf(fmaxf(smx[0], smx[1]), fmaxf(smx[2], smx[3]));
    mn = fminf(fminf(smn[0], smn[1]), fminf(smn[2], smn[3]));
    part[blockIdx.x] = mx;
    part[256 + blockIdx.x] = mn;
  }
}

__global__ void wminmax_final(const float* __restrict__ part, float* __restrict__ mm) {
  float mx = part[threadIdx.x];
  float mn = part[256 + threadIdx.x];
  #pragma unroll
  for (int o = 32; o > 0; o >>= 1) {
    mx = fmaxf(mx, __shfl_down(mx, o));
    mn = fminf(mn, __shfl_down(mn, o));
  }
  __shared__ float smx[4], smn[4];
  int lane = threadIdx.x & 63, wv = threadIdx.x >> 6;
  if (lane == 0) { smx[wv] = mx; smn[wv] = mn; }
  __syncthreads();
  if (threadIdx.x == 0) {
    mm[0] = fmaxf(fmaxf(smx[0], smx[1]), fmaxf(smx[2], smx[3]));
    mm[1] = fminf(fminf(smn[0], smn[1]), fminf(smn[2], smn[3]));
  }
}

// ---------- stage 3: fake-quant weight -> bf16 ----------
__global__ void quant_kernel(const float* __restrict__ w, const float* __restrict__ mm,
                             unsigned short* __restrict__ wq) {
  const float mx = mm[0], mn = mm[1];
  const float alpha = mx - mn, beta = mn;
  int i = (blockIdx.x * 256 + threadIdx.x) * 4;
  float4 v = *(const float4*)(w + i);
  float f[4] = {v.x, v.y, v.z, v.w};
  ushort4 o;
  unsigned short ov[4];
  #pragma unroll
  for (int j = 0; j < 4; j++) {
    float s = (f[j] - beta) / alpha;
    float R = rintf(15.0f * s) / 15.0f;
    float q = alpha * R + beta;
    if (f[j] == 0.0f) q = 0.0f;
    ov[j] = f2bf(q);
  }
  o.x = ov[0]; o.y = ov[1]; o.z = ov[2]; o.w = ov[3];
  *(ushort4*)(wq + i) = o;
}

// ---------- stage 3b: x f32 -> bf16 ----------
__global__ void conv_kernel(const float* __restrict__ x, unsigned short* __restrict__ xbf) {
  int i = (blockIdx.x * 256 + threadIdx.x) * 8;
  float4 a = *(const float4*)(x + i);
  float4 b = *(const float4*)(x + i + 4);
  union { v8s v; unsigned short u[8]; } o;
  o.u[0] = f2bf(a.x); o.u[1] = f2bf(a.y); o.u[2] = f2bf(a.z); o.u[3] = f2bf(a.w);
  o.u[4] = f2bf(b.x); o.u[5] = f2bf(b.y); o.u[6] = f2bf(b.z); o.u[7] = f2bf(b.w);
  *(v8s*)(xbf + i) = o.v;
}

// ---------- stage 4: 256x256 tile, BK=64, 8 waves, m201-style fine phases.
// LDS [buf][h][ks][128][32] sub-tiles (all accesses keep the proven
// conflict-free chunk-XOR swizzle). Per K-tile: 4 phases x {ds_reads ||
// 2 gload16 -> lgkmcnt(0)+sched_barrier -> setprio 16 MFMA}, with
// vmcnt(4)+s_barrier gates every 2 phases (counted; never drain in-loop).
__global__ __launch_bounds__(512, 2) void gemm8p_kernel(
    const unsigned short* __restrict__ xbf, const unsigned short* __restrict__ wq,
    const float* __restrict__ bias, float* __restrict__ out) {
  __shared__ __attribute__((aligned(16))) unsigned short As[2][2][2][128][32];  // 64KB
  __shared__ __attribute__((aligned(16))) unsigned short Bs[2][2][2][128][32];  // 64KB

  const int tid = threadIdx.x;
  const int lane = tid & 63;
  const int wv = tid >> 6;     // 0..7
  const int wr = wv >> 2;      // 0..1  (M half)
  const int wc = wv & 3;       // 0..3  (N quarter)
  const int bm = blockIdx.x;   // 0..63
  const int bn = blockIdx.y;   // 0..3

  // staging: wave wv stages rows [wv*16, wv*16+16) of every 128-row sub-tile.
  // LDS dest linear; global source chunk pre-swizzled by ((row>>1)&3).
  const int srow = wv * 16 + (lane >> 2);
  const int ssw = ((lane & 3) ^ ((lane >> 3) & 3)) * 8;
  const unsigned short* aS = xbf + (size_t)(bm * 256 + srow) * K_DIM + ssw;
  const unsigned short* bS = wq + (size_t)(bn * 256 + srow) * K_DIM + ssw;

  // fragment read addressing (swizzled), LDS byte addresses
  const int frow = lane & 15;
  const int kc = lane >> 4;
  const int fswB = (kc ^ ((frow >> 1) & 3)) * 16;
  const unsigned ldsA0 =
      (unsigned)(unsigned long long)(__attribute__((address_space(3))) unsigned short*)&As[0][0][0][0][0];
  const unsigned ldsB0 =
      (unsigned)(unsigned long long)(__attribute__((address_space(3))) unsigned short*)&Bs[0][0][0][0][0];
  const unsigned aLane = ldsA0 + wr * 16384u + (unsigned)(frow * 64 + fswB);
  const unsigned bLane = ldsB0 + (wc >> 1) * 16384u + (wc & 1) * 4096u + (unsigned)(frow * 64 + fswB);

  v4f acc[8][4];
  #pragma unroll
  for (int m = 0; m < 8; m++)
    #pragma unroll
    for (int n = 0; n < 4; n++) acc[m][n] = (v4f)(0.0f);

  v8s af[8], bf0, bf1;

#define GATE(N) do { \
    asm volatile("s_waitcnt vmcnt(" #N ")" ::: "memory"); \
    __builtin_amdgcn_s_barrier(); \
  } while (0)

#define MMX(NH) do { \
    asm volatile("s_waitcnt lgkmcnt(0)" ::: "memory"); \
    __builtin_amdgcn_sched_barrier(0); \
    __builtin_amdgcn_s_setprio(1); \
    _Pragma("unroll") \
    for (int m_ = 0; m_ < 8; m_++) { \
      acc[m_][2*(NH)]   = __builtin_amdgcn_mfma_f32_16x16x32_bf16(af[m_], bf0, acc[m_][2*(NH)], 0, 0, 0); \
      acc[m_][2*(NH)+1] = __builtin_amdgcn_mfma_f32_16x16x32_bf16(af[m_], bf1, acc[m_][2*(NH)+1], 0, 0, 0); \
    } \
    __builtin_amdgcn_s_setprio(0); \
  } while (0)

  // KSHALF: phases {ks,nh0} and {ks,nh1} of K-tile kt from buffer BUF.
  // Stages K-tile kt+1's matching ks sub-tiles into buffer BUF^1.
#define KSHALF(BUF, KS, ktv, STG) do { \
    const unsigned aP = aLane + (BUF) * 32768u + (KS) * 8192u; \
    const unsigned bP = bLane + (BUF) * 32768u + (KS) * 8192u; \
    DSR(af[0], aP, "0");    DSR(af[1], aP, "1024"); \
    DSR(af[2], aP, "2048"); DSR(af[3], aP, "3072"); \
    DSR(af[4], aP, "4096"); DSR(af[5], aP, "5120"); \
    DSR(af[6], aP, "6144"); DSR(af[7], aP, "7168"); \
    DSR(bf0, bP, "0");      DSR(bf1, bP, "1024"); \
    if (STG) { \
      gload16(aS + (size_t)(ktv + 1) * 64 + (KS) * 32, &As[(BUF) ^ 1][0][KS][wv * 16][0]); \
      gload16(aS + 131072 + (size_t)(ktv + 1) * 64 + (KS) * 32, &As[(BUF) ^ 1][1][KS][wv * 16][0]); \
    } \
    MMX(0); \
    DSR(bf0, bP, "2048");   DSR(bf1, bP, "3072"); \
    if (STG) { \
      gload16(bS + (size_t)(ktv + 1) * 64 + (KS) * 32, &Bs[(BUF) ^ 1][0][KS][wv * 16][0]); \
      gload16(bS + 131072 + (size_t)(ktv + 1) * 64 + (KS) * 32, &Bs[(BUF) ^ 1][1][KS][wv * 16][0]); \
    } \
    MMX(1); \
  } while (0)

#define KTILE(BUF, ktv, STG, GBN) do { \
    GATE(4); \
    KSHALF(BUF, 0, ktv, STG); \
    GATE(GBN); \
    KSHALF(BUF, 1, ktv, STG); \
  } while (0)

  // prologue: stage K-tile 0 in gate-invariant order (A-ks0, B-ks0, A-ks1, B-ks1)
  gload16(aS, &As[0][0][0][wv * 16][0]);
  gload16(aS + 131072, &As[0][1][0][wv * 16][0]);
  gload16(bS, &Bs[0][0][0][wv * 16][0]);
  gload16(bS + 131072, &Bs[0][1][0][wv * 16][0]);
  gload16(aS + 32, &As[0][0][1][wv * 16][0]);
  gload16(aS + 131072 + 32, &As[0][1][1][wv * 16][0]);
  gload16(bS + 32, &Bs[0][0][1][wv * 16][0]);
  gload16(bS + 131072 + 32, &Bs[0][1][1][wv * 16][0]);

  #pragma unroll 1
  for (int kt2 = 0; kt2 < 7; kt2++) {
    const int kt = kt2 * 2;
    KTILE(0, kt, 1, 4);
    KTILE(1, kt + 1, 1, 4);
  }
  KTILE(0, 14, 1, 4);
  KTILE(1, 15, 0, 0);

#undef KTILE
#undef KSHALF
#undef MMX
#undef GATE

  // C-write: col = lane&15, row = (lane>>4)*4 + reg  [m89-verified]
  const int colbase = bn * 256 + wc * 64;
  const int rowbase = bm * 256 + wr * 128;
  #pragma unroll
  for (int n = 0; n < 4; n++) {
    const int col = colbase + n * 16 + (lane & 15);
    const float bv = bias[col];
    #pragma unroll
    for (int m = 0; m < 8; m++) {
      const int row0 = rowbase + m * 16 + (lane >> 4) * 4;
      #pragma unroll
      for (int r = 0; r < 4; r++)
        out[(size_t)(row0 + r) * N_DIM + col] = acc[m][n][r] + bv;
    }
  }
}

// ---------- stage 4 (fallback if ws too small): round-2 proven kernel ----------
__global__ __launch_bounds__(256) void gemm_kernel(
    const float* __restrict__ x, const unsigned short* __restrict__ wq,
    const float* __restrict__ bias, float* __restrict__ out) {
  __shared__ __attribute__((aligned(16))) unsigned short As[2][128][32];
  __shared__ __attribute__((aligned(16))) unsigned short Bs[2][128][32];

  const int tid = threadIdx.x;
  const int lane = tid & 63;
  const int wv = tid >> 6;
  const int wr = wv >> 1, wc = wv & 1;
  const int bm = blockIdx.x, bn = blockIdx.y;

  const int arow = tid >> 1;
  const int acol = (tid & 1) << 4;
  const float* aptr = x + (size_t)(bm * 128 + arow) * K_DIM + acol;
  const int fA = (arow >> 1) & 3;
  const int ac0 = (tid & 1) * 2;
  const int aw0 = ((ac0) ^ fA) * 8;
  const int aw1 = ((ac0 + 1) ^ fA) * 8;

  const int brow0 = wv * 32 + (lane >> 2);
  const int bsrcc = (lane & 3) ^ ((lane >> 3) & 3);
  const unsigned short* bptr0 = wq + (size_t)(bn * 128 + brow0) * K_DIM + bsrcc * 8;
  const unsigned short* bptr1 = bptr0 + (size_t)16 * K_DIM;

  v4f acc[4][4];
  #pragma unroll
  for (int i = 0; i < 4; i++)
    #pragma unroll
    for (int j = 0; j < 4; j++) acc[i][j] = (v4f)(0.0f);

  const int frow = lane & 15;
  const int fkc = lane >> 4;
  const int fsw = (fkc ^ ((frow >> 1) & 3)) * 8;

  float4 areg[4];
  #pragma unroll
  for (int j = 0; j < 4; j++) areg[j] = *(const float4*)(aptr + j * 4);

  {
    const float* f = (const float*)areg;
    union { v8s v; unsigned short u[8]; } cv0, cv1;
    #pragma unroll
    for (int i = 0; i < 8; i++) { cv0.u[i] = f2bf(f[i]); cv1.u[i] = f2bf(f[i + 8]); }
    *(v8s*)&As[0][arow][aw0] = cv0.v;
    *(v8s*)&As[0][arow][aw1] = cv1.v;
    gload16(bptr0, &Bs[0][wv * 32][0]);
    gload16(bptr1, &Bs[0][wv * 32 + 16][0]);
  }
  #pragma unroll
  for (int j = 0; j < 4; j++) areg[j] = *(const float4*)(aptr + 32 + j * 4);
  __syncthreads();

  for (int kt = 0; kt < K_DIM / 32; ++kt) {
    const int cur = kt & 1, nxt = cur ^ 1;
    if (kt + 1 < K_DIM / 32) {
      const float* f = (const float*)areg;
      union { v8s v; unsigned short u[8]; } cv0, cv1;
      #pragma unroll
      for (int i = 0; i < 8; i++) { cv0.u[i] = f2bf(f[i]); cv1.u[i] = f2bf(f[i + 8]); }
      *(v8s*)&As[nxt][arow][aw0] = cv0.v;
      *(v8s*)&As[nxt][arow][aw1] = cv1.v;
      gload16(bptr0 + (size_t)(kt + 1) * 32, &Bs[nxt][wv * 32][0]);
      gload16(bptr1 + (size_t)(kt + 1) * 32, &Bs[nxt][wv * 32 + 16][0]);
      if (kt + 2 < K_DIM / 32) {
        const float* ap = aptr + (kt + 2) * 32;
        #pragma unroll
        for (int j = 0; j < 4; j++) areg[j] = *(const float4*)(ap + j * 4);
      }
    }
    v8s af[4], bf[4];
    #pragma unroll
    for (int m = 0; m < 4; m++)
      af[m] = *(const v8s*)&As[cur][wr * 64 + m * 16 + frow][fsw];
    #pragma unroll
    for (int n = 0; n < 4; n++)
      bf[n] = *(const v8s*)&Bs[cur][wc * 64 + n * 16 + frow][fsw];
    #pragma unroll
    for (int m = 0; m < 4; m++)
      #pragma unroll
      for (int n = 0; n < 4; n++)
        acc[m][n] = __builtin_amdgcn_mfma_f32_16x16x32_bf16(af[m], bf[n], acc[m][n], 0, 0, 0);
    __syncthreads();
  }

  const int colbase = bn * 128 + wc * 64;
  const int rowbase = bm * 128 + wr * 64;
  #pragma unroll
  for (int n = 0; n < 4; n++) {
    const int col = colbase + n * 16 + (lane & 15);
    const float bv = bias[col];
    #pragma unroll
    for (int m = 0; m < 4; m++) {
      const int row0 = rowbase + m * 16 + (lane >> 4) * 4;
      #pragma unroll
      for (int r = 0; r < 4; r++)
        out[(size_t)(row0 + r) * N_DIM + col] = acc[m][n][r] + bv;
    }
  }
}

extern "C" void kernel_launch(void* const* d_in, const int* in_sizes, int n_in,
                              void* d_out, int out_size, void* d_ws, size_t ws_size,
                              hipStream_t stream) {
  const float* x = (const float*)d_in[0];      // 16384 x 1024
  const float* wt = (const float*)d_in[1];     // 1024 x 1024 (n, m)
  const float* bias = (const float*)d_in[2];   // 1024
  float* out = (float*)d_out;                  // 16384 x 1024

  float* part = (float*)d_ws;
  float* mm = part + 512;
  unsigned short* wqbuf = (unsigned short*)((char*)d_ws + 4096);
  unsigned short* xbf = (unsigned short*)((char*)d_ws + 4096 + 2 * 1024 * 1024);
  const size_t need = 4096 + 2ull * 1024 * 1024 + 2ull * M_DIM * K_DIM;

  wminmax_part<<<256, 256, 0, stream>>>(wt, part);
  wminmax_final<<<1, 256, 0, stream>>>(part, mm);
  quant_kernel<<<1024, 256, 0, stream>>>(wt, mm, wqbuf);

  if (ws_size >= need) {
    conv_kernel<<<M_DIM * K_DIM / (8 * 256), 256, 0, stream>>>(x, xbf);
    dim3 grid(M_DIM / 256, N_DIM / 256);
    gemm8p_kernel<<<grid, 512, 0, stream>>>(xbf, wqbuf, bias, out);
  } else {
    dim3 grid(M_DIM / 128, N_DIM / 128);
    gemm_kernel<<<grid, 256, 0, stream>>>(x, wqbuf, bias, out);
  }
}